// Round 2
// baseline (888.266 us; speedup 1.0000x reference)
//
#include <hip/hip_runtime.h>

#define HH 112
#define WW 112
#define CIN 128
#define COUT 256

typedef __attribute__((ext_vector_type(8))) short bf16x8;
typedef __attribute__((ext_vector_type(4))) float f32x4;

__device__ __forceinline__ unsigned short f2bf(float f) {
    unsigned u = __builtin_bit_cast(unsigned, f);
    unsigned r = (u + 0x7FFFu + ((u >> 16) & 1u)) >> 16;
    return (unsigned short)r;
}

// Transpose+convert pw [128][256] f32 -> Bt [256][128] bf16 (in d_ws).
__global__ void prep_bt(const float* __restrict__ pw, unsigned short* __restrict__ bt) {
    int k = blockIdx.x;       // 0..127
    int n = threadIdx.x;      // 0..255
    bt[n * CIN + k] = f2bf(pw[k * COUT + n]);
}

// Fused depthwise 3x3 + pointwise 1x1.
// Block = 64-pixel tile (4 rows x 16 cols) x 256 output channels. 256 threads.
template <bool USE_WS>
__global__ __launch_bounds__(256, 2) void sepconv(
    const float* __restrict__ x, const float* __restrict__ dwk,
    const float* __restrict__ dwb, const unsigned short* __restrict__ Bt,
    const float* __restrict__ pw, const float* __restrict__ pwb,
    float* __restrict__ out) {
    __shared__ __align__(16) char Alds[64 * 256];  // 64 pixels x 128 bf16, swizzled

    const int tid = threadIdx.x;
    const int wid = tid >> 6;   // wave 0..3 -> output-channel slice of 64
    const int lane = tid & 63;
    const int lm = lane & 15;
    const int lg = lane >> 4;

    const int bid = blockIdx.x;
    const int nimg = bid / 196;
    const int rem = bid % 196;
    const int h0 = (rem / 7) * 4;
    const int w0 = (rem % 7) * 16;

    // ---- B fragments (persistent in regs); k = kk*32 + lg*8 + e ----
    bf16x8 bfrag[4][4];
    {
        const int nbase = wid * 64 + lm;
        const int kbase = lg * 8;
#pragma unroll
        for (int j = 0; j < 4; ++j)
#pragma unroll
            for (int kk = 0; kk < 4; ++kk) {
                if (USE_WS) {
                    bfrag[j][kk] = *(const bf16x8*)(Bt + (size_t)(nbase + j * 16) * CIN + kk * 32 + kbase);
                } else {
#pragma unroll
                    for (int e = 0; e < 8; ++e)
                        bfrag[j][kk][e] = (short)f2bf(pw[(size_t)(kk * 32 + kbase + e) * COUT + nbase + j * 16]);
                }
            }
    }

    // ---- depthwise: thread = (pixel p, 32-channel block cb) ----
    const int p = tid >> 2;        // 0..63
    const int cb = tid & 3;        // 0..3
    const int c0 = cb * 32;
    const int h = h0 + (p >> 4);
    const int w = w0 + (p & 15);

    float acc[32];
#pragma unroll
    for (int i = 0; i < 8; ++i) {
        f32x4 b = *(const f32x4*)(dwb + c0 + i * 4);
#pragma unroll
        for (int jj = 0; jj < 4; ++jj) acc[i * 4 + jj] = b[jj];
    }

#pragma unroll
    for (int kh = 0; kh < 3; ++kh) {
        int hh = h + kh - 1;
        if ((unsigned)hh >= HH) continue;
#pragma unroll
        for (int kw = 0; kw < 3; ++kw) {
            int ww = w + kw - 1;
            if ((unsigned)ww >= WW) continue;
            const float* xp = x + (((size_t)nimg * HH + hh) * WW + ww) * CIN + c0;
            const float* wp = dwk + (kh * 3 + kw) * CIN + c0;
#pragma unroll
            for (int i = 0; i < 8; ++i) {
                f32x4 xv = *(const f32x4*)(xp + i * 4);
                f32x4 wv = *(const f32x4*)(wp + i * 4);
#pragma unroll
                for (int jj = 0; jj < 4; ++jj) acc[i * 4 + jj] += xv[jj] * wv[jj];
            }
        }
    }

    // ---- y -> bf16 -> LDS (XOR-swizzled row of 256B) ----
    {
        bf16x8 yv[4];
#pragma unroll
        for (int q = 0; q < 4; ++q)
#pragma unroll
            for (int e = 0; e < 8; ++e) yv[q][e] = (short)f2bf(acc[q * 8 + e]);
        const int rowbase = p * 256;
        const int swz = (p & 7) << 4;
#pragma unroll
        for (int q = 0; q < 4; ++q) {
            int colb = c0 * 2 + q * 16;
            *(bf16x8*)(Alds + rowbase + (colb ^ swz)) = yv[q];
        }
    }
    __syncthreads();

    // ---- pointwise MFMA: out[64 x 64] per wave ----
    f32x4 dacc[4][4];
#pragma unroll
    for (int i = 0; i < 4; ++i)
#pragma unroll
        for (int j = 0; j < 4; ++j) {
            f32x4 z = {0.f, 0.f, 0.f, 0.f};
            dacc[i][j] = z;
        }

#pragma unroll
    for (int kk = 0; kk < 4; ++kk) {
        bf16x8 afrag[4];
#pragma unroll
        for (int i = 0; i < 4; ++i) {
            int m = i * 16 + lm;
            int colb = kk * 64 + lg * 16;
            afrag[i] = *(const bf16x8*)(Alds + m * 256 + (colb ^ ((m & 7) << 4)));
        }
#pragma unroll
        for (int i = 0; i < 4; ++i)
#pragma unroll
            for (int j = 0; j < 4; ++j)
                dacc[i][j] = __builtin_amdgcn_mfma_f32_16x16x32_bf16(
                    afrag[i], bfrag[j][kk], dacc[i][j], 0, 0, 0);
    }

    // ---- epilogue: +pw_bias, store fp32 ----
    float pb[4];
#pragma unroll
    for (int j = 0; j < 4; ++j) pb[j] = pwb[wid * 64 + j * 16 + lm];

#pragma unroll
    for (int i = 0; i < 4; ++i)
#pragma unroll
        for (int rr = 0; rr < 4; ++rr) {
            int m = i * 16 + lg * 4 + rr;
            int hh2 = h0 + (m >> 4);
            int ww2 = w0 + (m & 15);
            float* op = out + (((size_t)nimg * HH + hh2) * WW + ww2) * COUT + wid * 64 + lm;
#pragma unroll
            for (int j = 0; j < 4; ++j) op[j * 16] = dacc[i][j][rr] + pb[j];
        }
}

extern "C" void kernel_launch(void* const* d_in, const int* in_sizes, int n_in,
                              void* d_out, int out_size, void* d_ws, size_t ws_size,
                              hipStream_t stream) {
    const float* x   = (const float*)d_in[0];
    const float* dwk = (const float*)d_in[1];
    const float* dwb = (const float*)d_in[2];
    const float* pw  = (const float*)d_in[3];
    const float* pwb = (const float*)d_in[4];
    float* out = (float*)d_out;

    const int nimg = in_sizes[0] / (HH * WW * CIN);
    const int nblocks = nimg * 196;  // 28 row-tiles x 7 col-tiles per image

    if (ws_size >= (size_t)(COUT * CIN * sizeof(unsigned short))) {
        unsigned short* bt = (unsigned short*)d_ws;
        prep_bt<<<CIN, COUT, 0, stream>>>(pw, bt);
        sepconv<true><<<nblocks, 256, 0, stream>>>(x, dwk, dwb, bt, pw, pwb, out);
    } else {
        sepconv<false><<<nblocks, 256, 0, stream>>>(x, dwk, dwb, nullptr, pw, pwb, out);
    }
}